// Round 1
// 7115.849 us; speedup vs baseline: 1.4321x; 1.4321x over previous
//
#include <hip/hip_runtime.h>

#define SS 512
#define II 1024
#define HH 1024
#define NELEM (32 * SS * II)   // B*S*I elements of x

typedef short bf16x8 __attribute__((ext_vector_type(8)));
typedef float f32x4 __attribute__((ext_vector_type(4)));
typedef unsigned int u32;
typedef u32 u32x4 __attribute__((ext_vector_type(4)));

__device__ __forceinline__ short f2bf_s(float f) {
    union { float fv; u32 i; } v; v.fv = f;
    u32 r = v.i + 0x7FFF + ((v.i >> 16) & 1);  // RNE
    return (short)(r >> 16);
}
__device__ __forceinline__ float sigm(float x)   { return 1.0f / (1.0f + __expf(-x)); }
__device__ __forceinline__ float tanh_f(float x) { return 2.0f / (1.0f + __expf(-2.0f * x)) - 1.0f; }

__device__ __forceinline__ bf16x8 cvt8(const float* p) {
    bf16x8 r;
#pragma unroll
    for (int j = 0; j < 8; ++j) r[j] = f2bf_s(p[j]);
    return r;
}

// Pre-pass: x f32 -> bf16 (exactly covers NELEM with 8192 x 256 x 8)
__global__ void __launch_bounds__(256)
cvt_x_kernel(const float* __restrict__ x, ushort* __restrict__ xb) {
    const int i = (blockIdx.x * 256 + threadIdx.x) * 8;
    *(bf16x8*)(xb + i) = cvt8(x + i);
}

#define A_LD(p) __hip_atomic_load((p), __ATOMIC_RELAXED, __HIP_MEMORY_SCOPE_AGENT)
#define A_ST(p, v) __hip_atomic_store((p), (v), __ATOMIC_RELAXED, __HIP_MEMORY_SCOPE_AGENT)

// Persistent BiLSTM, flag-gated h exchange.
// Grid 256x256. Block g: dir d=g>>7, owns 8 h-units (32 gate-cols). Weights
// bf16 register-resident. h stored PACKED (2 bf16 units / dword).
//
// ROUND CHANGE (latency restructure): the old per-chunk confirm path
//   for it: { poll flag; reload chunk; MFMA }   (8 serial drained chains)
// was the dominant cost (~8 x 2.5us = measured 19.9us/step). Replaced with:
//   1) batched flag poll: all 8 flags per iteration, one round-trip per pass
//   2) after ALL flags confirmed: bulk-issue all 64 h dword loads in flight,
//      then MFMA (compiler pipelines vmcnt(N) across the 8 chunks)
//   3) out-store moved AFTER flag publication (waitcnt(0) no longer waits
//      an HBM store-ack before the flag becomes visible)
// h loads now issue only after flags are in registers => no stale-slot race.
template <int USE_XB>
__global__ void __launch_bounds__(256, 1)
bilstm_persist(const float* __restrict__ x,
               const float* __restrict__ Wii_f, const float* __restrict__ Whi_f,
               const float* __restrict__ bi_f,
               const float* __restrict__ Wii_r, const float* __restrict__ Whi_r,
               const float* __restrict__ bi_r,
               float* __restrict__ out, u32* __restrict__ hb,
               u32* __restrict__ flags, const ushort* __restrict__ xb)
{
    const int g   = blockIdx.x;
    const int d   = g >> 7;
    const int u0  = (g & 127) * 8;
    const int tid = threadIdx.x;
    const int w   = tid >> 6;
    const int l   = tid & 63;
    const int q   = l >> 4;
    const int ln  = l & 15;
    const int kw  = w * 256;
    const int pbase = d * 128 + (kw >> 3);   // first of this wave's 32 producers

    const float* Wx = d ? Wii_r : Wii_f;
    const float* Wh = d ? Whi_r : Whi_f;
    const float* bi = d ? bi_r  : bi_f;

    // Weight fragments: B-frag lane holds B[k=q*8+j][n=ln] = W[col n][k]
    bf16x8 wx[8][2], wh[8][2];
#pragma unroll
    for (int nt = 0; nt < 2; ++nt) {
        const int n = nt * 16 + ln;                    // local gate-col 0..31
        const int r = (n >> 3) * HH + u0 + (n & 7);    // W row: gate*H + unit
#pragma unroll
        for (int it = 0; it < 8; ++it) {
            const int off = r * 1024 + kw + it * 32 + q * 8;
            wx[it][nt] = cvt8(Wx + off);
            wh[it][nt] = cvt8(Wh + off);
        }
    }

    const int eb = tid >> 3;   // batch 0..31
    const int eu = tid & 7;    // local unit 0..7
    float bias[4];
#pragma unroll
    for (int gate = 0; gate < 4; ++gate)
        bias[gate] = bi[gate * HH + u0 + eu];

    float c_state = 0.0f;
    __shared__ float part[4][32][33];
    const f32x4 zero4 = {0.0f, 0.0f, 0.0f, 0.0f};

    for (int t = 0; t < SS; ++t) {
        const int tx = d ? (SS - 1 - t) : t;
        // packed slabs: slot*2+d, 32 rows x 512 dwords
        const u32* hrd = hb + (size_t)(((t & 1) ^ 1) * 2 + d) * 32 * 512;
        u32*       hwp = hb + (size_t)((t & 1) * 2 + d) * 32 * 512;

        f32x4 acc[2][2];
        acc[0][0] = zero4; acc[0][1] = zero4; acc[1][0] = zero4; acc[1][1] = zero4;

        u32 fl[8];
        const u32* fb  = flags + (size_t)(t - 1) * 256 + pbase + q; // +it*4
        const u32* hp0 = hrd + ln * 512 + (kw >> 1) + q * 4;        // +it*16

        if (t > 0) {
            // early speculative flag batch: all 8 in flight, overlapped
            // with the x-MFMA phase below
#pragma unroll
            for (int it = 0; it < 8; ++it) fl[it] = A_LD(fb + it * 4);
        }

        // ---- x part (independent of h) overlaps the flag loads ----
#pragma unroll
        for (int it = 0; it < 8; ++it) {
            const int ko = kw + it * 32 + q * 8;
            bf16x8 ax0, ax1;
            if (USE_XB) {
                ax0 = *(const bf16x8*)(xb + ((size_t)(ln * SS + tx)) * II + ko);
                ax1 = *(const bf16x8*)(xb + ((size_t)((16 + ln) * SS + tx)) * II + ko);
            } else {
                ax0 = cvt8(x + ((size_t)(ln * SS + tx)) * II + ko);
                ax1 = cvt8(x + ((size_t)((16 + ln) * SS + tx)) * II + ko);
            }
            acc[0][0] = __builtin_amdgcn_mfma_f32_16x16x32_bf16(ax0, wx[it][0], acc[0][0], 0, 0, 0);
            acc[0][1] = __builtin_amdgcn_mfma_f32_16x16x32_bf16(ax0, wx[it][1], acc[0][1], 0, 0, 0);
            acc[1][0] = __builtin_amdgcn_mfma_f32_16x16x32_bf16(ax1, wx[it][0], acc[1][0], 0, 0, 0);
            acc[1][1] = __builtin_amdgcn_mfma_f32_16x16x32_bf16(ax1, wx[it][1], acc[1][1], 0, 0, 0);
        }

        // ---- h part: batched flag wait, then bulk load, then MFMA ----
        if (t > 0) {
            // wave-level wait: lane checks its 8 producers; wave needs 32.
            // Flags are exactly 0u/1u so bitwise AND == logical AND.
            u32 m = fl[0] & fl[1] & fl[2] & fl[3] & fl[4] & fl[5] & fl[6] & fl[7];
            while (!__all(m != 0)) {
                __builtin_amdgcn_s_sleep(1);
#pragma unroll
                for (int it = 0; it < 8; ++it) fl[it] = A_LD(fb + it * 4);
                m = fl[0] & fl[1] & fl[2] & fl[3] & fl[4] & fl[5] & fl[6] & fl[7];
            }

            // all producers published and h is at the coherence point:
            // bulk-issue every h load, all 64 dwords/lane in flight at once
            u32x4 hr0[8], hr1[8];
#pragma unroll
            for (int it = 0; it < 8; ++it) {
#pragma unroll
                for (int j = 0; j < 4; ++j) {
                    hr0[it][j] = A_LD(hp0 + it * 16 + j);
                    hr1[it][j] = A_LD(hp0 + 16 * 512 + it * 16 + j);
                }
            }
#pragma unroll
            for (int it = 0; it < 8; ++it) {
                const bf16x8 ah0 = __builtin_bit_cast(bf16x8, hr0[it]);
                const bf16x8 ah1 = __builtin_bit_cast(bf16x8, hr1[it]);
                acc[0][0] = __builtin_amdgcn_mfma_f32_16x16x32_bf16(ah0, wh[it][0], acc[0][0], 0, 0, 0);
                acc[0][1] = __builtin_amdgcn_mfma_f32_16x16x32_bf16(ah0, wh[it][1], acc[0][1], 0, 0, 0);
                acc[1][0] = __builtin_amdgcn_mfma_f32_16x16x32_bf16(ah1, wh[it][0], acc[1][0], 0, 0, 0);
                acc[1][1] = __builtin_amdgcn_mfma_f32_16x16x32_bf16(ah1, wh[it][1], acc[1][1], 0, 0, 0);
            }
        }

        // C/D: reg r of lane = D[m=q*4+r][n=ln]
#pragma unroll
        for (int mt = 0; mt < 2; ++mt)
#pragma unroll
            for (int nt = 0; nt < 2; ++nt)
#pragma unroll
                for (int r4 = 0; r4 < 4; ++r4)
                    part[w][mt * 16 + q * 4 + r4][nt * 16 + ln] = acc[mt][nt][r4];
        __syncthreads();

        float gi[4];
#pragma unroll
        for (int gate = 0; gate < 4; ++gate) {
            float s = bias[gate];
#pragma unroll
            for (int w2 = 0; w2 < 4; ++w2) s += part[w2][eb][gate * 8 + eu];
            gi[gate] = s;
        }
        const float igate = sigm(gi[0]);
        const float fgate = sigm(gi[1]);
        const float ggate = tanh_f(gi[2]);
        const float ogate = sigm(gi[3]);
        c_state = fgate * c_state + igate * ggate;
        const float hv = ogate * tanh_f(c_state);

        // pack pair (even unit low, odd unit high) and publish h FIRST
        const u32 mine = (u32)(unsigned short)f2bf_s(hv);
        const u32 partner = (u32)__shfl_xor((int)mine, 1, 64);
        if ((tid & 1) == 0)
            A_ST(hwp + eb * 512 + ((u0 + eu) >> 1), mine | (partner << 16));

        __builtin_amdgcn_s_waitcnt(0);   // h stores ack'd at coherence point
        __syncthreads();                 // all 4 waves drained (also LDS reuse)
        if (tid == 0)
            A_ST(flags + (size_t)t * 256 + g, 1u);

        // out store AFTER the flag: off the publish critical path; it gets
        // drained (at the latest) by next step's waitcnt(0), a full step away
        out[((size_t)(eb * SS + tx)) * (2 * HH) + d * HH + u0 + eu] = hv;
    }
}

extern "C" void kernel_launch(void* const* d_in, const int* in_sizes, int n_in,
                              void* d_out, int out_size, void* d_ws, size_t ws_size,
                              hipStream_t stream)
{
    const float* x    = (const float*)d_in[0];
    const float* Wii  = (const float*)d_in[1];
    const float* Whi  = (const float*)d_in[2];
    const float* bi   = (const float*)d_in[3];
    const float* WiiR = (const float*)d_in[4];
    const float* WhiR = (const float*)d_in[5];
    const float* biR  = (const float*)d_in[6];
    float* out = (float*)d_out;

    // ws: [0,256K) packed h ping-pong (2 slots x 2 dir x 32 b x 512 dwords)
    //     [256K,768K) flags (512 steps x 256 blocks, write-once)
    //     [1M, 1M+32M) bf16 x copy
    u32* hb    = (u32*)d_ws;
    u32* flags = (u32*)((char*)d_ws + 256 * 1024);
    ushort* xb = (ushort*)((char*)d_ws + 1024 * 1024);
    const int use_xb = (ws_size >= 1024 * 1024 + (size_t)NELEM * 2) ? 1 : 0;

    hipMemsetAsync(d_ws, 0, 768 * 1024, stream);   // zero h slabs + flags

    if (use_xb) {
        hipLaunchKernelGGL(cvt_x_kernel, dim3(NELEM / (256 * 8)), dim3(256), 0, stream, x, xb);
        hipLaunchKernelGGL((bilstm_persist<1>), dim3(256), dim3(256), 0, stream,
                           x, Wii, Whi, bi, WiiR, WhiR, biR, out, hb, flags, xb);
    } else {
        hipLaunchKernelGGL((bilstm_persist<0>), dim3(256), dim3(256), 0, stream,
                           x, Wii, Whi, bi, WiiR, WhiR, biR, out, hb, flags, xb);
    }
}

// Round 2
// 4036.345 us; speedup vs baseline: 2.5248x; 1.7629x over previous
//
#include <hip/hip_runtime.h>

#define SS 512
#define II 1024
#define HH 1024
#define NELEM (32 * SS * II)   // B*S*I elements of x

typedef short bf16x8 __attribute__((ext_vector_type(8)));
typedef float f32x4 __attribute__((ext_vector_type(4)));
typedef unsigned int u32;
typedef u32 u32x4 __attribute__((ext_vector_type(4)));

__device__ __forceinline__ short f2bf_s(float f) {
    union { float fv; u32 i; } v; v.fv = f;
    u32 r = v.i + 0x7FFF + ((v.i >> 16) & 1);  // RNE
    return (short)(r >> 16);
}
__device__ __forceinline__ float sigm(float x)   { return 1.0f / (1.0f + __expf(-x)); }
__device__ __forceinline__ float tanh_f(float x) { return 2.0f / (1.0f + __expf(-2.0f * x)) - 1.0f; }

__device__ __forceinline__ bf16x8 cvt8(const float* p) {
    bf16x8 r;
#pragma unroll
    for (int j = 0; j < 8; ++j) r[j] = f2bf_s(p[j]);
    return r;
}

// Pre-pass: x f32 -> bf16 (exactly covers NELEM with 8192 x 256 x 8)
__global__ void __launch_bounds__(256)
cvt_x_kernel(const float* __restrict__ x, ushort* __restrict__ xb) {
    const int i = (blockIdx.x * 256 + threadIdx.x) * 8;
    *(bf16x8*)(xb + i) = cvt8(x + i);
}

#define A_LD(p) __hip_atomic_load((p), __ATOMIC_RELAXED, __HIP_MEMORY_SCOPE_AGENT)
#define A_ST(p, v) __hip_atomic_store((p), (v), __ATOMIC_RELAXED, __HIP_MEMORY_SCOPE_AGENT)

// Device-coherent vectorized 16B load (same sc0+sc1 policy the agent-scope
// relaxed atomic loads compile to, but 4 dwords per instruction and issued
// as an explicitly ordered back-to-back batch -> ONE round trip for the
// whole h slab instead of the compiler's register-rationed rolling window).
#define HLOAD(dst, base, OFF)                                              \
    asm volatile("global_load_dwordx4 %0, %1, off offset:" #OFF " sc0 sc1" \
                 : "=v"(dst) : "v"(base) : "memory")

// Persistent BiLSTM, flag-gated h exchange.
// Grid 256x256. Block g: dir d=g>>7, owns 8 h-units (32 gate-cols). Weights
// bf16 register-resident. h stored PACKED (2 bf16 units / dword).
//
// ROUND CHANGE: round-1 counters showed VGPR_Count=156 while the bulk h
// load needs ~215 live regs -> compiler serialized the "bulk" load into a
// rolling window of ~2-3 coherence-point round trips (~2.5us each). This
// round forces a true single-round-trip bulk load: 16 inline-asm
// global_load_dwordx4 sc0 sc1 (vs 64 scalar dword atomics), one
// s_waitcnt vmcnt(0), then the 32 h-MFMAs. Protocol (flags, producer
// waitcnt(0), ping-pong slots) unchanged from the verified round-1 kernel.
template <int USE_XB>
__global__ void __launch_bounds__(256, 1)
bilstm_persist(const float* __restrict__ x,
               const float* __restrict__ Wii_f, const float* __restrict__ Whi_f,
               const float* __restrict__ bi_f,
               const float* __restrict__ Wii_r, const float* __restrict__ Whi_r,
               const float* __restrict__ bi_r,
               float* __restrict__ out, u32* __restrict__ hb,
               u32* __restrict__ flags, const ushort* __restrict__ xb)
{
    const int g   = blockIdx.x;
    const int d   = g >> 7;
    const int u0  = (g & 127) * 8;
    const int tid = threadIdx.x;
    const int w   = tid >> 6;
    const int l   = tid & 63;
    const int q   = l >> 4;
    const int ln  = l & 15;
    const int kw  = w * 256;
    const int pbase = d * 128 + (kw >> 3);   // first of this wave's 32 producers

    const float* Wx = d ? Wii_r : Wii_f;
    const float* Wh = d ? Whi_r : Whi_f;
    const float* bi = d ? bi_r  : bi_f;

    // Weight fragments: B-frag lane holds B[k=q*8+j][n=ln] = W[col n][k]
    bf16x8 wx[8][2], wh[8][2];
#pragma unroll
    for (int nt = 0; nt < 2; ++nt) {
        const int n = nt * 16 + ln;                    // local gate-col 0..31
        const int r = (n >> 3) * HH + u0 + (n & 7);    // W row: gate*H + unit
#pragma unroll
        for (int it = 0; it < 8; ++it) {
            const int off = r * 1024 + kw + it * 32 + q * 8;
            wx[it][nt] = cvt8(Wx + off);
            wh[it][nt] = cvt8(Wh + off);
        }
    }

    const int eb = tid >> 3;   // batch 0..31
    const int eu = tid & 7;    // local unit 0..7
    float bias[4];
#pragma unroll
    for (int gate = 0; gate < 4; ++gate)
        bias[gate] = bi[gate * HH + u0 + eu];

    float c_state = 0.0f;
    __shared__ float part[4][32][33];
    const f32x4 zero4 = {0.0f, 0.0f, 0.0f, 0.0f};

    for (int t = 0; t < SS; ++t) {
        const int tx = d ? (SS - 1 - t) : t;
        // packed slabs: slot*2+d, 32 rows x 512 dwords
        const u32* hrd = hb + (size_t)(((t & 1) ^ 1) * 2 + d) * 32 * 512;
        u32*       hwp = hb + (size_t)((t & 1) * 2 + d) * 32 * 512;

        f32x4 acc[2][2];
        acc[0][0] = zero4; acc[0][1] = zero4; acc[1][0] = zero4; acc[1][1] = zero4;

        u32 fl[8];
        const u32* fb  = flags + (size_t)(t - 1) * 256 + pbase + q; // +it*4
        const u32* hp0 = hrd + ln * 512 + (kw >> 1) + q * 4;        // +it*16

        if (t > 0) {
            // early speculative flag batch: all 8 in flight, overlapped
            // with the x-MFMA phase below
#pragma unroll
            for (int it = 0; it < 8; ++it) fl[it] = A_LD(fb + it * 4);
        }

        // ---- x part (independent of h) overlaps the flag loads ----
#pragma unroll
        for (int it = 0; it < 8; ++it) {
            const int ko = kw + it * 32 + q * 8;
            bf16x8 ax0, ax1;
            if (USE_XB) {
                ax0 = *(const bf16x8*)(xb + ((size_t)(ln * SS + tx)) * II + ko);
                ax1 = *(const bf16x8*)(xb + ((size_t)((16 + ln) * SS + tx)) * II + ko);
            } else {
                ax0 = cvt8(x + ((size_t)(ln * SS + tx)) * II + ko);
                ax1 = cvt8(x + ((size_t)((16 + ln) * SS + tx)) * II + ko);
            }
            acc[0][0] = __builtin_amdgcn_mfma_f32_16x16x32_bf16(ax0, wx[it][0], acc[0][0], 0, 0, 0);
            acc[0][1] = __builtin_amdgcn_mfma_f32_16x16x32_bf16(ax0, wx[it][1], acc[0][1], 0, 0, 0);
            acc[1][0] = __builtin_amdgcn_mfma_f32_16x16x32_bf16(ax1, wx[it][0], acc[1][0], 0, 0, 0);
            acc[1][1] = __builtin_amdgcn_mfma_f32_16x16x32_bf16(ax1, wx[it][1], acc[1][1], 0, 0, 0);
        }

        // ---- h part: batched flag wait, then ONE-round-trip bulk load ----
        if (t > 0) {
            // wave-level wait: lane checks its 8 producers; wave needs 32.
            // Flags are exactly 0u/1u so bitwise AND == logical AND.
            u32 m = fl[0] & fl[1] & fl[2] & fl[3] & fl[4] & fl[5] & fl[6] & fl[7];
            while (!__all(m != 0)) {
                __builtin_amdgcn_s_sleep(1);
#pragma unroll
                for (int it = 0; it < 8; ++it) fl[it] = A_LD(fb + it * 4);
                m = fl[0] & fl[1] & fl[2] & fl[3] & fl[4] & fl[5] & fl[6] & fl[7];
            }

            // flags confirmed => h is ack'd at the coherence point (producer
            // drained stores before flag). Issue ALL 16 dwordx4 coherent
            // loads back-to-back (volatile asm preserves issue order), then
            // a single vmcnt(0): the whole 16KB/wave slab costs one RT.
            const u32* hbase0 = hp0;               // rows ln
            const u32* hbase1 = hp0 + 16 * 512;    // rows ln+16
            u32x4 h4a[8], h4b[8];
            HLOAD(h4a[0], hbase0, 0);
            HLOAD(h4a[1], hbase0, 64);
            HLOAD(h4a[2], hbase0, 128);
            HLOAD(h4a[3], hbase0, 192);
            HLOAD(h4a[4], hbase0, 256);
            HLOAD(h4a[5], hbase0, 320);
            HLOAD(h4a[6], hbase0, 384);
            HLOAD(h4a[7], hbase0, 448);
            HLOAD(h4b[0], hbase1, 0);
            HLOAD(h4b[1], hbase1, 64);
            HLOAD(h4b[2], hbase1, 128);
            HLOAD(h4b[3], hbase1, 192);
            HLOAD(h4b[4], hbase1, 256);
            HLOAD(h4b[5], hbase1, 320);
            HLOAD(h4b[6], hbase1, 384);
            HLOAD(h4b[7], hbase1, 448);
            asm volatile("s_waitcnt vmcnt(0)" ::: "memory");
            __builtin_amdgcn_sched_barrier(0);     // rule #18: pin MFMAs after wait

#pragma unroll
            for (int it = 0; it < 8; ++it) {
                const bf16x8 ah0 = __builtin_bit_cast(bf16x8, h4a[it]);
                const bf16x8 ah1 = __builtin_bit_cast(bf16x8, h4b[it]);
                acc[0][0] = __builtin_amdgcn_mfma_f32_16x16x32_bf16(ah0, wh[it][0], acc[0][0], 0, 0, 0);
                acc[0][1] = __builtin_amdgcn_mfma_f32_16x16x32_bf16(ah0, wh[it][1], acc[0][1], 0, 0, 0);
                acc[1][0] = __builtin_amdgcn_mfma_f32_16x16x32_bf16(ah1, wh[it][0], acc[1][0], 0, 0, 0);
                acc[1][1] = __builtin_amdgcn_mfma_f32_16x16x32_bf16(ah1, wh[it][1], acc[1][1], 0, 0, 0);
            }
        }

        // C/D: reg r of lane = D[m=q*4+r][n=ln]
#pragma unroll
        for (int mt = 0; mt < 2; ++mt)
#pragma unroll
            for (int nt = 0; nt < 2; ++nt)
#pragma unroll
                for (int r4 = 0; r4 < 4; ++r4)
                    part[w][mt * 16 + q * 4 + r4][nt * 16 + ln] = acc[mt][nt][r4];
        __syncthreads();

        float gi[4];
#pragma unroll
        for (int gate = 0; gate < 4; ++gate) {
            float s = bias[gate];
#pragma unroll
            for (int w2 = 0; w2 < 4; ++w2) s += part[w2][eb][gate * 8 + eu];
            gi[gate] = s;
        }
        const float igate = sigm(gi[0]);
        const float fgate = sigm(gi[1]);
        const float ggate = tanh_f(gi[2]);
        const float ogate = sigm(gi[3]);
        c_state = fgate * c_state + igate * ggate;
        const float hv = ogate * tanh_f(c_state);

        // pack pair (even unit low, odd unit high) and publish h FIRST
        const u32 mine = (u32)(unsigned short)f2bf_s(hv);
        const u32 partner = (u32)__shfl_xor((int)mine, 1, 64);
        if ((tid & 1) == 0)
            A_ST(hwp + eb * 512 + ((u0 + eu) >> 1), mine | (partner << 16));

        __builtin_amdgcn_s_waitcnt(0);   // h stores ack'd at coherence point
        __syncthreads();                 // all 4 waves drained (also LDS reuse)
        if (tid == 0)
            A_ST(flags + (size_t)t * 256 + g, 1u);

        // out store AFTER the flag: off the publish critical path; it gets
        // drained (at the latest) by next step's waitcnt(0), a full step away
        out[((size_t)(eb * SS + tx)) * (2 * HH) + d * HH + u0 + eu] = hv;
    }
}

extern "C" void kernel_launch(void* const* d_in, const int* in_sizes, int n_in,
                              void* d_out, int out_size, void* d_ws, size_t ws_size,
                              hipStream_t stream)
{
    const float* x    = (const float*)d_in[0];
    const float* Wii  = (const float*)d_in[1];
    const float* Whi  = (const float*)d_in[2];
    const float* bi   = (const float*)d_in[3];
    const float* WiiR = (const float*)d_in[4];
    const float* WhiR = (const float*)d_in[5];
    const float* biR  = (const float*)d_in[6];
    float* out = (float*)d_out;

    // ws: [0,256K) packed h ping-pong (2 slots x 2 dir x 32 b x 512 dwords)
    //     [256K,768K) flags (512 steps x 256 blocks, write-once)
    //     [1M, 1M+32M) bf16 x copy
    u32* hb    = (u32*)d_ws;
    u32* flags = (u32*)((char*)d_ws + 256 * 1024);
    ushort* xb = (ushort*)((char*)d_ws + 1024 * 1024);
    const int use_xb = (ws_size >= 1024 * 1024 + (size_t)NELEM * 2) ? 1 : 0;

    hipMemsetAsync(d_ws, 0, 768 * 1024, stream);   // zero h slabs + flags

    if (use_xb) {
        hipLaunchKernelGGL(cvt_x_kernel, dim3(NELEM / (256 * 8)), dim3(256), 0, stream, x, xb);
        hipLaunchKernelGGL((bilstm_persist<1>), dim3(256), dim3(256), 0, stream,
                           x, Wii, Whi, bi, WiiR, WhiR, biR, out, hb, flags, xb);
    } else {
        hipLaunchKernelGGL((bilstm_persist<0>), dim3(256), dim3(256), 0, stream,
                           x, Wii, Whi, bi, WiiR, WhiR, biR, out, hb, flags, xb);
    }
}